// Round 1
// baseline (904.583 us; speedup 1.0000x reference)
//
#include <hip/hip_runtime.h>
#include <hip/hip_bf16.h>
#include <math.h>

#define NEG 0.2f

__device__ __forceinline__ float fsig(float x){ return 1.0f/(1.0f+__expf(-x)); }
__device__ __forceinline__ float ftanh(float x){ float e = __expf(2.0f*x); return 1.0f - 2.0f/(e+1.0f); }

// ---- K0: probe whether edge_index is stored as int64 (odd int32 words all 0) or int32
__global__ void k_probe(const int* __restrict__ ei, int* __restrict__ flag){
    if(threadIdx.x==0){
        int nz=0;
        for(int i=0;i<64;i++) nz |= ei[2*i+1];
        *flag = (nz==0) ? 1 : 0;  // 1 => int64 storage
    }
}

// ---- K2: xs = x @ W   (x:[n,128], W:[128,128])
__global__ __launch_bounds__(256) void k_gemm_xs(const float* __restrict__ x,
                                                 const float* __restrict__ W,
                                                 float* __restrict__ xs, int n){
    __shared__ float xl[32*128];
    const int t = threadIdx.x;
    const int r0 = blockIdx.x*32;
    for(int i=0;i<16;i++){
        int f = t + i*256;
        int row = r0 + (f>>7);
        xl[f] = (row<n) ? x[(size_t)row*128 + (f&127)] : 0.0f;
    }
    __syncthreads();
    const int col = t & 127, rg = t>>7;
    float acc[16];
    #pragma unroll
    for(int r=0;r<16;r++) acc[r]=0.f;
    for(int k4=0;k4<32;k4++){
        float w0 = W[(4*k4+0)*128+col];
        float w1 = W[(4*k4+1)*128+col];
        float w2 = W[(4*k4+2)*128+col];
        float w3 = W[(4*k4+3)*128+col];
        #pragma unroll
        for(int r=0;r<16;r++){
            const float4 xv = *(const float4*)&xl[(rg*16+r)*128 + 4*k4];
            acc[r] += xv.x*w0 + xv.y*w1 + xv.z*w2 + xv.w*w3;
        }
    }
    #pragma unroll
    for(int r=0;r<16;r++){
        int row = r0 + rg*16 + r;
        if(row<n) xs[(size_t)row*128+col] = acc[r];
    }
}

// ---- K3: a_src[row] = xs[row,:]·att_src ; a_dst likewise. One wave per row.
__global__ __launch_bounds__(256) void k_attdot(const float* __restrict__ xs,
                                                const float* __restrict__ as,
                                                const float* __restrict__ ad,
                                                float* __restrict__ a_src,
                                                float* __restrict__ a_dst, int n){
    const int wv = threadIdx.x>>6, l = threadIdx.x&63;
    const int row = blockIdx.x*4 + wv;
    if(row>=n) return;
    float x0 = xs[(size_t)row*128+l], x1 = xs[(size_t)row*128+64+l];
    float ps = x0*as[l] + x1*as[64+l];
    float pd = x0*ad[l] + x1*ad[64+l];
    for(int off=32;off;off>>=1){ ps += __shfl_xor(ps,off); pd += __shfl_xor(pd,off); }
    if(l==0){ a_src[row]=ps; a_dst[row]=pd; }
}

// ---- K4: per-edge logit -> exp -> atomic sum per dst
__global__ __launch_bounds__(256) void k_edge1(const int* __restrict__ ei,
                                               const float* __restrict__ a_src,
                                               const float* __restrict__ a_dst,
                                               const int* __restrict__ flag,
                                               float* __restrict__ e_exp,
                                               float* __restrict__ e_sum,
                                               int E, int EN){
    int e = blockIdx.x*256 + threadIdx.x;
    if(e>=EN) return;
    int src,dst;
    if(e>=E){ src=dst=e-E; }
    else if(*flag){ src = ei[2*e]; dst = ei[2*(E+e)]; }
    else         { src = ei[e];   dst = ei[E+e]; }
    float s = a_src[src]+a_dst[dst];
    s = s>=0.f ? s : NEG*s;                 // leaky relu
    float p = __expf(s);                    // no max-shift: |s| <~ 10, safe in f32
    e_exp[e]=p;
    unsafeAtomicAdd(&e_sum[dst], p);
}

// ---- K5: gat_acc[dst,:] += alpha * xs[src,:]  -- one wave per edge
__global__ __launch_bounds__(256) void k_edge2(const int* __restrict__ ei,
                                               const float* __restrict__ xs,
                                               const float* __restrict__ e_exp,
                                               const float* __restrict__ e_sum,
                                               const int* __restrict__ flag,
                                               float* __restrict__ acc,
                                               int E, int EN){
    const int wv = threadIdx.x>>6, l = threadIdx.x&63;
    const int e = blockIdx.x*4 + wv;
    if(e>=EN) return;
    int src,dst;
    if(e>=E){ src=dst=e-E; }
    else if(*flag){ src = ei[2*e]; dst = ei[2*(E+e)]; }
    else         { src = ei[e];   dst = ei[E+e]; }
    const float alpha = e_exp[e]/(e_sum[dst]+1e-16f);
    const float2 v = *(const float2*)&xs[(size_t)src*128 + 2*l];
    unsafeAtomicAdd(&acc[(size_t)dst*128+2*l  ], alpha*v.x);
    unsafeAtomicAdd(&acc[(size_t)dst*128+2*l+1], alpha*v.y);
}

// ---- K6: transpose LSTM weights -> WT[k][j], k<128: W_ih, k>=128: W_hh (j in [0,512))
__global__ __launch_bounds__(256) void k_wt(const float* __restrict__ W_ih,
                                            const float* __restrict__ W_hh,
                                            float* __restrict__ WT){
    int f = blockIdx.x*256+threadIdx.x;   // 256*512 elements
    int k = f>>9, j = f&511;
    WT[f] = (k<128) ? W_ih[j*128+k] : W_hh[j*128+(k-128)];
}

// ---- K7: LSTM: gates = tanh(gacc+bias) @ W_ih^T + h0 @ W_hh^T ; activations; outputs
__global__ __launch_bounds__(256) void k_lstm(const float* __restrict__ gacc,
                                              const float* __restrict__ bias,
                                              const float* __restrict__ h0,
                                              const float* __restrict__ c0,
                                              const float* __restrict__ WT,
                                              float* __restrict__ out, int n){
    __shared__ float sm[16*512];          // 32 KB; first 4096 floats double as xh[16][256]
    const int t = threadIdx.x;
    const int r0 = blockIdx.x*16;
    for(int i=0;i<16;i++){
        int f = t + i*256;                 // 4096 = 16*256
        int r = f>>8, kk = f&255;
        int row = r0+r; if(row>=n) row = n-1;
        float v;
        if(kk<128) v = ftanh(gacc[(size_t)row*128+kk] + bias[kk]);
        else       v = h0[(size_t)row*128 + kk-128];
        sm[f] = v;
    }
    __syncthreads();
    float acc0[16], acc1[16];
    #pragma unroll
    for(int r=0;r<16;r++){ acc0[r]=0.f; acc1[r]=0.f; }
    const int ca = t, cb = t+256;
    for(int k4=0;k4<64;k4++){
        float wa0 = WT[(4*k4+0)*512 + ca];
        float wa1 = WT[(4*k4+1)*512 + ca];
        float wa2 = WT[(4*k4+2)*512 + ca];
        float wa3 = WT[(4*k4+3)*512 + ca];
        float wb0 = WT[(4*k4+0)*512 + cb];
        float wb1 = WT[(4*k4+1)*512 + cb];
        float wb2 = WT[(4*k4+2)*512 + cb];
        float wb3 = WT[(4*k4+3)*512 + cb];
        #pragma unroll
        for(int r=0;r<16;r++){
            const float4 xv = *(const float4*)&sm[r*256 + 4*k4];
            acc0[r] += xv.x*wa0 + xv.y*wa1 + xv.z*wa2 + xv.w*wa3;
            acc1[r] += xv.x*wb0 + xv.y*wb1 + xv.z*wb2 + xv.w*wb3;
        }
    }
    __syncthreads();
    #pragma unroll
    for(int r=0;r<16;r++){ sm[r*512 + ca] = acc0[r]; sm[r*512 + cb] = acc1[r]; }
    __syncthreads();
    for(int i=0;i<8;i++){
        int f = t + i*256;                 // 2048 = 16*128
        int r = f>>7, d = f&127;
        int row = r0+r;
        if(row>=n) continue;
        float gi = sm[r*512 +       d];
        float gf = sm[r*512 + 128 + d];
        float gg = sm[r*512 + 256 + d];
        float go = sm[r*512 + 384 + d];
        float cc = c0[(size_t)row*128+d];
        float c1v = fsig(gf)*cc + fsig(gi)*ftanh(gg);
        float h1v = fsig(go)*ftanh(c1v);
        out[(size_t)row*128+d]               = h1v;  // out0 = xb*0 + h1
        out[(size_t)n*128 + (size_t)row*128+d] = h1v;  // out1 = h1[None]
        out[(size_t)2*n*128 + (size_t)row*128+d] = c1v; // out2 = c1[None]
    }
}

extern "C" void kernel_launch(void* const* d_in, const int* in_sizes, int n_in,
                              void* d_out, int out_size, void* d_ws, size_t ws_size,
                              hipStream_t stream) {
    const float* x      = (const float*)d_in[0];
    const int*   ei     = (const int*)  d_in[1];
    const float* h      = (const float*)d_in[2];
    const float* c      = (const float*)d_in[3];
    const float* W      = (const float*)d_in[4];
    const float* atts   = (const float*)d_in[5];
    const float* attd   = (const float*)d_in[6];
    const float* bias   = (const float*)d_in[7];
    const float* W_ih   = (const float*)d_in[8];
    const float* W_hh   = (const float*)d_in[9];
    float* out = (float*)d_out;

    const int n  = in_sizes[0]/128;
    const int E  = in_sizes[1]/2;
    const int EN = E + n;

    float* ws    = (float*)d_ws;
    float* xs    = ws;                         // n*128
    float* gacc  = xs   + (size_t)n*128;       // n*128
    float* a_src = gacc + (size_t)n*128;       // n
    float* a_dst = a_src + n;                  // n
    float* e_sum = a_dst + n;                  // n
    float* e_exp = e_sum + n;                  // EN
    float* WT    = e_exp + EN;                 // 256*512
    int*   flag  = (int*)(WT + 256*512);       // 1

    hipMemsetAsync(gacc, 0, (size_t)n*128*sizeof(float), stream);
    hipMemsetAsync(e_sum, 0, (size_t)n*sizeof(float), stream);
    k_probe<<<1,64,0,stream>>>(ei, flag);
    k_gemm_xs<<<(n+31)/32,256,0,stream>>>(x,W,xs,n);
    k_attdot<<<(n+3)/4,256,0,stream>>>(xs,atts,attd,a_src,a_dst,n);
    k_wt<<<512,256,0,stream>>>(W_ih,W_hh,WT);
    k_edge1<<<(EN+255)/256,256,0,stream>>>(ei,a_src,a_dst,flag,e_exp,e_sum,E,EN);
    k_edge2<<<(EN+3)/4,256,0,stream>>>(ei,xs,e_exp,e_sum,flag,gacc,E,EN);
    k_lstm<<<(n+15)/16,256,0,stream>>>(gacc,bias,h,c,WT,out,n);
}

// Round 2
// 472.471 us; speedup vs baseline: 1.9146x; 1.9146x over previous
//
#include <hip/hip_runtime.h>
#include <hip/hip_bf16.h>
#include <math.h>

#define NEG 0.2f

__device__ __forceinline__ float fsig(float x){ return 1.0f/(1.0f+__expf(-x)); }
__device__ __forceinline__ float ftanh(float x){ float e = __expf(2.0f*x); return 1.0f - 2.0f/(e+1.0f); }

// ---- K0: probe whether edge_index is stored as int64 (odd int32 words all 0) or int32
__global__ void k_probe(const int* __restrict__ ei, int* __restrict__ flag){
    if(threadIdx.x==0){
        int nz=0;
        for(int i=0;i<64;i++) nz |= ei[2*i+1];
        *flag = (nz==0) ? 1 : 0;  // 1 => int64 storage
    }
}

// ---- K2: xs = x @ W   (x:[n,128], W:[128,128])
__global__ __launch_bounds__(256) void k_gemm_xs(const float* __restrict__ x,
                                                 const float* __restrict__ W,
                                                 float* __restrict__ xs, int n){
    __shared__ float xl[32*128];
    const int t = threadIdx.x;
    const int r0 = blockIdx.x*32;
    for(int i=0;i<16;i++){
        int f = t + i*256;
        int row = r0 + (f>>7);
        xl[f] = (row<n) ? x[(size_t)row*128 + (f&127)] : 0.0f;
    }
    __syncthreads();
    const int col = t & 127, rg = t>>7;
    float acc[16];
    #pragma unroll
    for(int r=0;r<16;r++) acc[r]=0.f;
    for(int k4=0;k4<32;k4++){
        float w0 = W[(4*k4+0)*128+col];
        float w1 = W[(4*k4+1)*128+col];
        float w2 = W[(4*k4+2)*128+col];
        float w3 = W[(4*k4+3)*128+col];
        #pragma unroll
        for(int r=0;r<16;r++){
            const float4 xv = *(const float4*)&xl[(rg*16+r)*128 + 4*k4];
            acc[r] += xv.x*w0 + xv.y*w1 + xv.z*w2 + xv.w*w3;
        }
    }
    #pragma unroll
    for(int r=0;r<16;r++){
        int row = r0 + rg*16 + r;
        if(row<n) xs[(size_t)row*128+col] = acc[r];
    }
}

// ---- K3: a_src[row] = xs[row,:]·att_src ; a_dst likewise. One wave per row.
__global__ __launch_bounds__(256) void k_attdot(const float* __restrict__ xs,
                                                const float* __restrict__ as,
                                                const float* __restrict__ ad,
                                                float* __restrict__ a_src,
                                                float* __restrict__ a_dst, int n){
    const int wv = threadIdx.x>>6, l = threadIdx.x&63;
    const int row = blockIdx.x*4 + wv;
    if(row>=n) return;
    float x0 = xs[(size_t)row*128+l], x1 = xs[(size_t)row*128+64+l];
    float ps = x0*as[l] + x1*as[64+l];
    float pd = x0*ad[l] + x1*ad[64+l];
    for(int off=32;off;off>>=1){ ps += __shfl_xor(ps,off); pd += __shfl_xor(pd,off); }
    if(l==0){ a_src[row]=ps; a_dst[row]=pd; }
}

// ---- CSR build: histogram of dst (self-loops appended: dst = e-E)
__global__ __launch_bounds__(256) void k_hist(const int* __restrict__ ei,
                                              const int* __restrict__ flag,
                                              int* __restrict__ deg, int E, int EN){
    int e = blockIdx.x*256 + threadIdx.x;
    if(e>=EN) return;
    int dst = (e>=E) ? (e-E) : (*flag ? ei[2*(E+e)] : ei[E+e]);
    atomicAdd(&deg[dst], 1);
}

// ---- scan level 1: per-512-chunk sums
__global__ __launch_bounds__(256) void k_scan1(const int* __restrict__ deg,
                                               int* __restrict__ bsum, int n){
    __shared__ int ws[4];
    int b = blockIdx.x, t = threadIdx.x;
    int i = b*512 + t*2;
    int s = 0;
    if(i<n)   s += deg[i];
    if(i+1<n) s += deg[i+1];
    for(int off=32;off;off>>=1) s += __shfl_xor(s,off);
    if((t&63)==0) ws[t>>6]=s;
    __syncthreads();
    if(t==0) bsum[b]=ws[0]+ws[1]+ws[2]+ws[3];
}

// ---- scan level 2: exclusive scan of up to 128 block sums (one wave)
__global__ void k_scan2(int* __restrict__ bsum, int* __restrict__ rowptr,
                        int nb, int n, int EN){
    int t = threadIdx.x;  // 64
    int v0 = (t<nb)    ? bsum[t]    : 0;
    int v1 = (64+t<nb) ? bsum[64+t] : 0;
    int x = v0;
    for(int d=1; d<64; d<<=1){ int y=__shfl_up(x,d); if(t>=d) x+=y; }
    int tot0 = __shfl(x,63);
    int x1 = v1;
    for(int d=1; d<64; d<<=1){ int y=__shfl_up(x1,d); if(t>=d) x1+=y; }
    if(t<nb)    bsum[t]    = x - v0;
    if(64+t<nb) bsum[64+t] = tot0 + x1 - v1;
    if(t==0) rowptr[n]=EN;
}

// ---- scan level 3: in-chunk exclusive scan + block offset -> rowptr, cursor
__global__ __launch_bounds__(256) void k_scan3(const int* __restrict__ deg,
                                               const int* __restrict__ bsum,
                                               int* __restrict__ rowptr,
                                               int* __restrict__ cursor, int n){
    __shared__ int wsum[4];
    int b = blockIdx.x, t = threadIdx.x;
    int i = b*512 + t*2;
    int d0 = (i<n)?deg[i]:0, d1 = (i+1<n)?deg[i+1]:0;
    int s = d0+d1;
    int x = s;
    int lane = t&63, wv = t>>6;
    for(int dd=1; dd<64; dd<<=1){ int y=__shfl_up(x,dd); if(lane>=dd) x+=y; }
    if(lane==63) wsum[wv]=x;
    __syncthreads();
    int woff=0;
    for(int w=0;w<wv;w++) woff += wsum[w];
    int ex = bsum[b] + woff + x - s;     // exclusive prefix for element i
    if(i<n)   { rowptr[i]  =ex;    cursor[i]  =ex;    }
    if(i+1<n) { rowptr[i+1]=ex+d0; cursor[i+1]=ex+d0; }
}

// ---- fill CSR: csr_src[pos] = src for each edge grouped by dst
__global__ __launch_bounds__(256) void k_fill(const int* __restrict__ ei,
                                              const int* __restrict__ flag,
                                              int* __restrict__ cursor,
                                              int* __restrict__ csr_src, int E, int EN){
    int e = blockIdx.x*256 + threadIdx.x;
    if(e>=EN) return;
    int src,dst;
    if(e>=E){ src=dst=e-E; }
    else if(*flag){ src = ei[2*e]; dst = ei[2*(E+e)]; }
    else         { src = ei[e];   dst = ei[E+e]; }
    int pos = atomicAdd(&cursor[dst], 1);
    csr_src[pos] = src;
}

// ---- aggregate: one wave per dst node; acc = (sum_j p_j * xs[src_j]) / sum_j p_j
__global__ __launch_bounds__(256) void k_agg(const int* __restrict__ rowptr,
                                             const int* __restrict__ csr_src,
                                             const float* __restrict__ a_src,
                                             const float* __restrict__ a_dst,
                                             const float* __restrict__ xs,
                                             float* __restrict__ acc, int n){
    const int wv = threadIdx.x>>6, l = threadIdx.x&63;
    const int dst = blockIdx.x*4 + wv;
    if(dst>=n) return;
    const int beg = rowptr[dst], end = rowptr[dst+1];
    const float ad = a_dst[dst];
    float ax=0.f, ay=0.f, psum=0.f;
    for(int j=beg;j<end;j++){
        int s = csr_src[j];
        float sv = a_src[s] + ad;
        sv = sv>=0.f ? sv : NEG*sv;
        float p = __expf(sv);
        psum += p;
        const float2 v = *(const float2*)&xs[(size_t)s*128 + 2*l];
        ax += p*v.x; ay += p*v.y;
    }
    const float inv = 1.0f/(psum + 1e-16f);
    *(float2*)&acc[(size_t)dst*128 + 2*l] = make_float2(ax*inv, ay*inv);
}

// ---- K6: transpose LSTM weights -> WT[k][j], k<128: W_ih, k>=128: W_hh (j in [0,512))
__global__ __launch_bounds__(256) void k_wt(const float* __restrict__ W_ih,
                                            const float* __restrict__ W_hh,
                                            float* __restrict__ WT){
    int f = blockIdx.x*256+threadIdx.x;   // 256*512 elements
    int k = f>>9, j = f&511;
    WT[f] = (k<128) ? W_ih[j*128+k] : W_hh[j*128+(k-128)];
}

// ---- K7: LSTM: gates = tanh(gacc+bias) @ W_ih^T + h0 @ W_hh^T ; activations; outputs
__global__ __launch_bounds__(256) void k_lstm(const float* __restrict__ gacc,
                                              const float* __restrict__ bias,
                                              const float* __restrict__ h0,
                                              const float* __restrict__ c0,
                                              const float* __restrict__ WT,
                                              float* __restrict__ out, int n){
    __shared__ float sm[16*512];          // 32 KB; first 4096 floats double as xh[16][256]
    const int t = threadIdx.x;
    const int r0 = blockIdx.x*16;
    for(int i=0;i<16;i++){
        int f = t + i*256;                 // 4096 = 16*256
        int r = f>>8, kk = f&255;
        int row = r0+r; if(row>=n) row = n-1;
        float v;
        if(kk<128) v = ftanh(gacc[(size_t)row*128+kk] + bias[kk]);
        else       v = h0[(size_t)row*128 + kk-128];
        sm[f] = v;
    }
    __syncthreads();
    float acc0[16], acc1[16];
    #pragma unroll
    for(int r=0;r<16;r++){ acc0[r]=0.f; acc1[r]=0.f; }
    const int ca = t, cb = t+256;
    for(int k4=0;k4<64;k4++){
        float wa0 = WT[(4*k4+0)*512 + ca];
        float wa1 = WT[(4*k4+1)*512 + ca];
        float wa2 = WT[(4*k4+2)*512 + ca];
        float wa3 = WT[(4*k4+3)*512 + ca];
        float wb0 = WT[(4*k4+0)*512 + cb];
        float wb1 = WT[(4*k4+1)*512 + cb];
        float wb2 = WT[(4*k4+2)*512 + cb];
        float wb3 = WT[(4*k4+3)*512 + cb];
        #pragma unroll
        for(int r=0;r<16;r++){
            const float4 xv = *(const float4*)&sm[r*256 + 4*k4];
            acc0[r] += xv.x*wa0 + xv.y*wa1 + xv.z*wa2 + xv.w*wa3;
            acc1[r] += xv.x*wb0 + xv.y*wb1 + xv.z*wb2 + xv.w*wb3;
        }
    }
    __syncthreads();
    #pragma unroll
    for(int r=0;r<16;r++){ sm[r*512 + ca] = acc0[r]; sm[r*512 + cb] = acc1[r]; }
    __syncthreads();
    for(int i=0;i<8;i++){
        int f = t + i*256;                 // 2048 = 16*128
        int r = f>>7, d = f&127;
        int row = r0+r;
        if(row>=n) continue;
        float gi = sm[r*512 +       d];
        float gf = sm[r*512 + 128 + d];
        float gg = sm[r*512 + 256 + d];
        float go = sm[r*512 + 384 + d];
        float cc = c0[(size_t)row*128+d];
        float c1v = fsig(gf)*cc + fsig(gi)*ftanh(gg);
        float h1v = fsig(go)*ftanh(c1v);
        out[(size_t)row*128+d]               = h1v;  // out0 = xb*0 + h1
        out[(size_t)n*128 + (size_t)row*128+d] = h1v;  // out1 = h1[None]
        out[(size_t)2*n*128 + (size_t)row*128+d] = c1v; // out2 = c1[None]
    }
}

extern "C" void kernel_launch(void* const* d_in, const int* in_sizes, int n_in,
                              void* d_out, int out_size, void* d_ws, size_t ws_size,
                              hipStream_t stream) {
    const float* x      = (const float*)d_in[0];
    const int*   ei     = (const int*)  d_in[1];
    const float* h      = (const float*)d_in[2];
    const float* c      = (const float*)d_in[3];
    const float* W      = (const float*)d_in[4];
    const float* atts   = (const float*)d_in[5];
    const float* attd   = (const float*)d_in[6];
    const float* bias   = (const float*)d_in[7];
    const float* W_ih   = (const float*)d_in[8];
    const float* W_hh   = (const float*)d_in[9];
    float* out = (float*)d_out;

    const int n  = in_sizes[0]/128;
    const int E  = in_sizes[1]/2;
    const int EN = E + n;
    const int NB = (n + 511)/512;          // scan chunks (<=128 for n<=65536)

    float* ws    = (float*)d_ws;
    float* xs    = ws;                         // n*128
    float* gacc  = xs   + (size_t)n*128;       // n*128
    float* a_src = gacc + (size_t)n*128;       // n
    float* a_dst = a_src + n;                  // n
    float* WT    = a_dst + n;                  // 256*512
    int*   deg    = (int*)(WT + 256*512);      // n
    int*   rowptr = deg + n;                   // n+1
    int*   cursor = rowptr + n + 1;            // n
    int*   bsum   = cursor + n;                // 128
    int*   csr_src= bsum + 128;                // EN
    int*   flag   = csr_src + EN;              // 1

    hipMemsetAsync(deg, 0, (size_t)n*sizeof(int), stream);
    k_probe<<<1,64,0,stream>>>(ei, flag);
    k_gemm_xs<<<(n+31)/32,256,0,stream>>>(x,W,xs,n);
    k_attdot<<<(n+3)/4,256,0,stream>>>(xs,atts,attd,a_src,a_dst,n);
    k_wt<<<512,256,0,stream>>>(W_ih,W_hh,WT);
    k_hist<<<(EN+255)/256,256,0,stream>>>(ei,flag,deg,E,EN);
    k_scan1<<<NB,256,0,stream>>>(deg,bsum,n);
    k_scan2<<<1,64,0,stream>>>(bsum,rowptr,NB,n,EN);
    k_scan3<<<NB,256,0,stream>>>(deg,bsum,rowptr,cursor,n);
    k_fill<<<(EN+255)/256,256,0,stream>>>(ei,flag,cursor,csr_src,E,EN);
    k_agg<<<(n+3)/4,256,0,stream>>>(rowptr,csr_src,a_src,a_dst,xs,gacc,n);
    k_lstm<<<(n+15)/16,256,0,stream>>>(gacc,bias,h,c,WT,out,n);
}

// Round 3
// 277.426 us; speedup vs baseline: 3.2606x; 1.7031x over previous
//
#include <hip/hip_runtime.h>
#include <hip/hip_bf16.h>
#include <math.h>

#define NEG 0.2f

typedef float f32x4 __attribute__((ext_vector_type(4)));
typedef short bf16x8 __attribute__((ext_vector_type(8)));

__device__ __forceinline__ float fsig(float x){ return 1.0f/(1.0f+__expf(-x)); }
__device__ __forceinline__ float ftanh(float x){ float e = __expf(2.0f*x); return 1.0f - 2.0f/(e+1.0f); }
__device__ __forceinline__ unsigned short f2bf(float v){
    __hip_bfloat16 b = __float2bfloat16(v);
    return *(unsigned short*)&b;
}

// ---- K0: probe whether edge_index is stored as int64 (odd int32 words all 0) or int32
__global__ void k_probe(const int* __restrict__ ei, int* __restrict__ flag){
    if(threadIdx.x==0){
        int nz=0;
        for(int i=0;i<64;i++) nz |= ei[2*i+1];
        *flag = (nz==0) ? 1 : 0;  // 1 => int64 storage
    }
}

// ---- K2: xs = x @ W   (x:[n,128], W:[128,128])
__global__ __launch_bounds__(256) void k_gemm_xs(const float* __restrict__ x,
                                                 const float* __restrict__ W,
                                                 float* __restrict__ xs, int n){
    __shared__ float xl[32*128];
    const int t = threadIdx.x;
    const int r0 = blockIdx.x*32;
    for(int i=0;i<16;i++){
        int f = t + i*256;
        int row = r0 + (f>>7);
        xl[f] = (row<n) ? x[(size_t)row*128 + (f&127)] : 0.0f;
    }
    __syncthreads();
    const int col = t & 127, rg = t>>7;
    float acc[16];
    #pragma unroll
    for(int r=0;r<16;r++) acc[r]=0.f;
    for(int k4=0;k4<32;k4++){
        float w0 = W[(4*k4+0)*128+col];
        float w1 = W[(4*k4+1)*128+col];
        float w2 = W[(4*k4+2)*128+col];
        float w3 = W[(4*k4+3)*128+col];
        #pragma unroll
        for(int r=0;r<16;r++){
            const float4 xv = *(const float4*)&xl[(rg*16+r)*128 + 4*k4];
            acc[r] += xv.x*w0 + xv.y*w1 + xv.z*w2 + xv.w*w3;
        }
    }
    #pragma unroll
    for(int r=0;r<16;r++){
        int row = r0 + rg*16 + r;
        if(row<n) xs[(size_t)row*128+col] = acc[r];
    }
}

// ---- K3: a_src[row] = xs[row,:]·att_src ; a_dst likewise. One wave per row.
__global__ __launch_bounds__(256) void k_attdot(const float* __restrict__ xs,
                                                const float* __restrict__ as,
                                                const float* __restrict__ ad,
                                                float* __restrict__ a_src,
                                                float* __restrict__ a_dst, int n){
    const int wv = threadIdx.x>>6, l = threadIdx.x&63;
    const int row = blockIdx.x*4 + wv;
    if(row>=n) return;
    float x0 = xs[(size_t)row*128+l], x1 = xs[(size_t)row*128+64+l];
    float ps = x0*as[l] + x1*as[64+l];
    float pd = x0*ad[l] + x1*ad[64+l];
    for(int off=32;off;off>>=1){ ps += __shfl_xor(ps,off); pd += __shfl_xor(pd,off); }
    if(l==0){ a_src[row]=ps; a_dst[row]=pd; }
}

// ---- CSR build: histogram of dst (self-loops appended: dst = e-E)
__global__ __launch_bounds__(256) void k_hist(const int* __restrict__ ei,
                                              const int* __restrict__ flag,
                                              int* __restrict__ deg, int E, int EN){
    int e = blockIdx.x*256 + threadIdx.x;
    if(e>=EN) return;
    int dst = (e>=E) ? (e-E) : (*flag ? ei[2*(E+e)] : ei[E+e]);
    atomicAdd(&deg[dst], 1);
}

// ---- scan level 1: per-512-chunk sums
__global__ __launch_bounds__(256) void k_scan1(const int* __restrict__ deg,
                                               int* __restrict__ bsum, int n){
    __shared__ int ws[4];
    int b = blockIdx.x, t = threadIdx.x;
    int i = b*512 + t*2;
    int s = 0;
    if(i<n)   s += deg[i];
    if(i+1<n) s += deg[i+1];
    for(int off=32;off;off>>=1) s += __shfl_xor(s,off);
    if((t&63)==0) ws[t>>6]=s;
    __syncthreads();
    if(t==0) bsum[b]=ws[0]+ws[1]+ws[2]+ws[3];
}

// ---- scan level 2: exclusive scan of up to 128 block sums (one wave)
__global__ void k_scan2(int* __restrict__ bsum, int* __restrict__ rowptr,
                        int nb, int n, int EN){
    int t = threadIdx.x;  // 64
    int v0 = (t<nb)    ? bsum[t]    : 0;
    int v1 = (64+t<nb) ? bsum[64+t] : 0;
    int x = v0;
    for(int d=1; d<64; d<<=1){ int y=__shfl_up(x,d); if(t>=d) x+=y; }
    int tot0 = __shfl(x,63);
    int x1 = v1;
    for(int d=1; d<64; d<<=1){ int y=__shfl_up(x1,d); if(t>=d) x1+=y; }
    if(t<nb)    bsum[t]    = x - v0;
    if(64+t<nb) bsum[64+t] = tot0 + x1 - v1;
    if(t==0) rowptr[n]=EN;
}

// ---- scan level 3: in-chunk exclusive scan + block offset -> rowptr, cursor
__global__ __launch_bounds__(256) void k_scan3(const int* __restrict__ deg,
                                               const int* __restrict__ bsum,
                                               int* __restrict__ rowptr,
                                               int* __restrict__ cursor, int n){
    __shared__ int wsum[4];
    int b = blockIdx.x, t = threadIdx.x;
    int i = b*512 + t*2;
    int d0 = (i<n)?deg[i]:0, d1 = (i+1<n)?deg[i+1]:0;
    int s = d0+d1;
    int x = s;
    int lane = t&63, wv = t>>6;
    for(int dd=1; dd<64; dd<<=1){ int y=__shfl_up(x,dd); if(lane>=dd) x+=y; }
    if(lane==63) wsum[wv]=x;
    __syncthreads();
    int woff=0;
    for(int w=0;w<wv;w++) woff += wsum[w];
    int ex = bsum[b] + woff + x - s;     // exclusive prefix for element i
    if(i<n)   { rowptr[i]  =ex;    cursor[i]  =ex;    }
    if(i+1<n) { rowptr[i+1]=ex+d0; cursor[i+1]=ex+d0; }
}

// ---- fill CSR: csr_src[pos] = src for each edge grouped by dst
__global__ __launch_bounds__(256) void k_fill(const int* __restrict__ ei,
                                              const int* __restrict__ flag,
                                              int* __restrict__ cursor,
                                              int* __restrict__ csr_src, int E, int EN){
    int e = blockIdx.x*256 + threadIdx.x;
    if(e>=EN) return;
    int src,dst;
    if(e>=E){ src=dst=e-E; }
    else if(*flag){ src = ei[2*e]; dst = ei[2*(E+e)]; }
    else         { src = ei[e];   dst = ei[E+e]; }
    int pos = atomicAdd(&cursor[dst], 1);
    csr_src[pos] = src;
}

// ---- aggregate: one wave per dst node; acc = (sum_j p_j * xs[src_j]) / sum_j p_j
__global__ __launch_bounds__(256) void k_agg(const int* __restrict__ rowptr,
                                             const int* __restrict__ csr_src,
                                             const float* __restrict__ a_src,
                                             const float* __restrict__ a_dst,
                                             const float* __restrict__ xs,
                                             float* __restrict__ acc, int n){
    const int wv = threadIdx.x>>6, l = threadIdx.x&63;
    const int dst = blockIdx.x*4 + wv;
    if(dst>=n) return;
    const int beg = rowptr[dst], end = rowptr[dst+1];
    const float ad = a_dst[dst];
    float ax=0.f, ay=0.f, psum=0.f;
    for(int j=beg;j<end;j++){
        int s = csr_src[j];
        float sv = a_src[s] + ad;
        sv = sv>=0.f ? sv : NEG*sv;
        float p = __expf(sv);
        psum += p;
        const float2 v = *(const float2*)&xs[(size_t)s*128 + 2*l];
        ax += p*v.x; ay += p*v.y;
    }
    const float inv = 1.0f/(psum + 1e-16f);
    *(float2*)&acc[(size_t)dst*128 + 2*l] = make_float2(ax*inv, ay*inv);
}

// ---- pack LSTM weights into bf16 MFMA B-fragment order.
// B[k][j]: k<128 -> W_ih[j][k], k>=128 -> W_hh[j][k-128]   (j in [0,512))
// frag f = (ks*32+ct)*64+lane holds B[ks*32+(lane>>4)*8+jj][ct*16+(lane&15)], jj=0..7
__global__ __launch_bounds__(256) void k_wtpack(const float* __restrict__ W_ih,
                                                const float* __restrict__ W_hh,
                                                unsigned short* __restrict__ WP){
    int f = blockIdx.x*256 + threadIdx.x;      // 16384 frags
    int lane = f&63, ct = (f>>6)&31, ks = f>>11;
    int k0 = ks*32 + (lane>>4)*8;
    int col = ct*16 + (lane&15);
    unsigned short v[8];
    #pragma unroll
    for(int jj=0;jj<8;jj++){
        int k = k0+jj;
        float w = (k<128) ? W_ih[col*128+k] : W_hh[col*128+(k-128)];
        v[jj] = f2bf(w);
    }
    #pragma unroll
    for(int jj=0;jj<8;jj++) WP[(size_t)f*8+jj] = v[jj];
}

// ---- K7 (MFMA): gates = [tanh(gacc+bias) | h0] @ B ; activations; outputs
// block = 64 rows x 512 cols, 4 waves; wave w owns rows w*16..w*16+15 (all cols)
__global__ __launch_bounds__(256) void k_lstm2(const float* __restrict__ gacc,
                                               const float* __restrict__ bias,
                                               const float* __restrict__ h0,
                                               const float* __restrict__ c0,
                                               const unsigned short* __restrict__ WP,
                                               float* __restrict__ out, int n){
    __shared__ unsigned short xh[64*256];      // 32 KB, XOR-swizzled 16B chunks
    __shared__ unsigned short Bb[32*512];      // 32 KB, one k-step of B frags
    const int t = threadIdx.x;
    const int w = t>>6, l = t&63;
    const int r0 = blockIdx.x*64;

    // phase 1: xh[row][k] = k<128 ? tanh(gacc[row][k]+bias[k]) : h0[row][k-128]
    for(int i=0;i<8;i++){
        int chunk = t + i*256;                 // 2048 chunks of 8 bf16
        int row = chunk>>5, c8 = chunk&31;
        int grow = r0+row; if(grow>=n) grow = n-1;
        unsigned short pk[8];
        if(c8<16){
            const float4 v0 = *(const float4*)&gacc[(size_t)grow*128 + c8*8];
            const float4 v1 = *(const float4*)&gacc[(size_t)grow*128 + c8*8 + 4];
            pk[0]=f2bf(ftanh(v0.x+bias[c8*8+0])); pk[1]=f2bf(ftanh(v0.y+bias[c8*8+1]));
            pk[2]=f2bf(ftanh(v0.z+bias[c8*8+2])); pk[3]=f2bf(ftanh(v0.w+bias[c8*8+3]));
            pk[4]=f2bf(ftanh(v1.x+bias[c8*8+4])); pk[5]=f2bf(ftanh(v1.y+bias[c8*8+5]));
            pk[6]=f2bf(ftanh(v1.z+bias[c8*8+6])); pk[7]=f2bf(ftanh(v1.w+bias[c8*8+7]));
        }else{
            const float4 v0 = *(const float4*)&h0[(size_t)grow*128 + (c8-16)*8];
            const float4 v1 = *(const float4*)&h0[(size_t)grow*128 + (c8-16)*8 + 4];
            pk[0]=f2bf(v0.x); pk[1]=f2bf(v0.y); pk[2]=f2bf(v0.z); pk[3]=f2bf(v0.w);
            pk[4]=f2bf(v1.x); pk[5]=f2bf(v1.y); pk[6]=f2bf(v1.z); pk[7]=f2bf(v1.w);
        }
        int boff = row*512 + ((c8*16) ^ ((row&7)<<4));   // bytes
        *(bf16x8*)((char*)xh + boff) = *(bf16x8*)pk;
    }
    __syncthreads();

    f32x4 acc[32];
    #pragma unroll
    for(int i=0;i<32;i++) acc[i] = (f32x4){0.f,0.f,0.f,0.f};

    const int arow = w*16 + (l&15);            // LDS row for A frag
    for(int ks=0;ks<8;ks++){
        // stage B k-step: 32KB straight copy (frag order)
        const float4* gsrc = (const float4*)(WP + (size_t)ks*16384);
        #pragma unroll
        for(int i=0;i<8;i++){
            ((float4*)Bb)[t + i*256] = gsrc[t + i*256];
        }
        __syncthreads();
        int aoff = arow*512 + ((ks*64 + (l>>4)*16) ^ ((arow&7)<<4));
        const bf16x8 a = *(const bf16x8*)((char*)xh + aoff);
        #pragma unroll
        for(int ct=0;ct<32;ct++){
            const bf16x8 b = *(const bf16x8*)((char*)Bb + (ct*64 + l)*16);
            acc[ct] = __builtin_amdgcn_mfma_f32_16x16x32_bf16(a, b, acc[ct], 0, 0, 0);
        }
        __syncthreads();
    }

    // epilogue: lane holds gi=acc[ct], gf=acc[ct+8], gg=acc[ct+16], go=acc[ct+24]
    const size_t nn = (size_t)n*128;
    #pragma unroll
    for(int ct=0;ct<8;ct++){
        int col = ct*16 + (l&15);
        #pragma unroll
        for(int reg=0;reg<4;reg++){
            int row = r0 + w*16 + (l>>4)*4 + reg;
            if(row>=n) continue;
            float gi = acc[ct][reg], gf = acc[ct+8][reg];
            float gg = acc[ct+16][reg], go = acc[ct+24][reg];
            float cc = c0[(size_t)row*128+col];
            float c1v = fsig(gf)*cc + fsig(gi)*ftanh(gg);
            float h1v = fsig(go)*ftanh(c1v);
            out[(size_t)row*128+col]        = h1v;
            out[nn + (size_t)row*128+col]   = h1v;
            out[2*nn + (size_t)row*128+col] = c1v;
        }
    }
}

extern "C" void kernel_launch(void* const* d_in, const int* in_sizes, int n_in,
                              void* d_out, int out_size, void* d_ws, size_t ws_size,
                              hipStream_t stream) {
    const float* x      = (const float*)d_in[0];
    const int*   ei     = (const int*)  d_in[1];
    const float* h      = (const float*)d_in[2];
    const float* c      = (const float*)d_in[3];
    const float* W      = (const float*)d_in[4];
    const float* atts   = (const float*)d_in[5];
    const float* attd   = (const float*)d_in[6];
    const float* bias   = (const float*)d_in[7];
    const float* W_ih   = (const float*)d_in[8];
    const float* W_hh   = (const float*)d_in[9];
    float* out = (float*)d_out;

    const int n  = in_sizes[0]/128;
    const int E  = in_sizes[1]/2;
    const int EN = E + n;
    const int NB = (n + 511)/512;

    float* ws    = (float*)d_ws;
    float* xs    = ws;                         // n*128
    float* gacc  = xs   + (size_t)n*128;       // n*128
    float* a_src = gacc + (size_t)n*128;       // n
    float* a_dst = a_src + n;                  // n
    unsigned short* WP = (unsigned short*)(a_dst + n);   // 131072 bf16 (=65536 f32)
    int*   deg    = (int*)(WP + 131072);       // n
    int*   rowptr = deg + n;                   // n+1
    int*   cursor = rowptr + n + 1;            // n
    int*   bsum   = cursor + n;                // 128
    int*   csr_src= bsum + 128;                // EN
    int*   flag   = csr_src + EN;              // 1

    hipMemsetAsync(deg, 0, (size_t)n*sizeof(int), stream);
    k_probe<<<1,64,0,stream>>>(ei, flag);
    k_gemm_xs<<<(n+31)/32,256,0,stream>>>(x,W,xs,n);
    k_attdot<<<(n+3)/4,256,0,stream>>>(xs,atts,attd,a_src,a_dst,n);
    k_wtpack<<<64,256,0,stream>>>(W_ih,W_hh,WP);
    k_hist<<<(EN+255)/256,256,0,stream>>>(ei,flag,deg,E,EN);
    k_scan1<<<NB,256,0,stream>>>(deg,bsum,n);
    k_scan2<<<1,64,0,stream>>>(bsum,rowptr,NB,n,EN);
    k_scan3<<<NB,256,0,stream>>>(deg,bsum,rowptr,cursor,n);
    k_fill<<<(EN+255)/256,256,0,stream>>>(ei,flag,cursor,csr_src,E,EN);
    k_agg<<<(n+3)/4,256,0,stream>>>(rowptr,csr_src,a_src,a_dst,xs,gacc,n);
    k_lstm2<<<(n+63)/64,256,0,stream>>>(gacc,bias,h,c,WP,out,n);
}

// Round 4
// 237.048 us; speedup vs baseline: 3.8160x; 1.1703x over previous
//
#include <hip/hip_runtime.h>
#include <hip/hip_bf16.h>
#include <math.h>

#define NEG 0.2f

typedef float f32x4 __attribute__((ext_vector_type(4)));
typedef short bf16x8 __attribute__((ext_vector_type(8)));

__device__ __forceinline__ float fsig(float x){ return 1.0f/(1.0f+__expf(-x)); }
__device__ __forceinline__ float ftanh(float x){ float e = __expf(2.0f*x); return 1.0f - 2.0f/(e+1.0f); }
__device__ __forceinline__ unsigned short f2bf(float v){
    __hip_bfloat16 b = __float2bfloat16(v);
    return *(unsigned short*)&b;
}
__device__ __forceinline__ bf16x8 pack8(float4 u, float4 v){
    bf16x8 r;
    r[0]=(short)f2bf(u.x); r[1]=(short)f2bf(u.y); r[2]=(short)f2bf(u.z); r[3]=(short)f2bf(u.w);
    r[4]=(short)f2bf(v.x); r[5]=(short)f2bf(v.y); r[6]=(short)f2bf(v.z); r[7]=(short)f2bf(v.w);
    return r;
}

// ---- K0: probe whether edge_index is stored as int64 (odd int32 words all 0) or int32
__global__ void k_probe(const int* __restrict__ ei, int* __restrict__ flag){
    if(threadIdx.x==0){
        int nz=0;
        for(int i=0;i<64;i++) nz |= ei[2*i+1];
        *flag = (nz==0) ? 1 : 0;  // 1 => int64 storage
    }
}

// ---- pack W (xs GEMM) into MFMA B-frag order: frag f=(ks*8+ct), lane l, j:
// B[k=ks*32+(l>>4)*8+j][col=ct*16+(l&15)] = W[k][col]
__global__ __launch_bounds__(256) void k_wpackx(const float* __restrict__ W,
                                                unsigned short* __restrict__ WPX){
    int f = blockIdx.x*256 + threadIdx.x;      // 2048 thread-frags
    int l = f&63, ct = (f>>6)&7, ks = f>>9;
    int k0 = ks*32 + (l>>4)*8;
    int col = ct*16 + (l&15);
    #pragma unroll
    for(int j=0;j<8;j++) WPX[(size_t)f*8+j] = f2bf(W[(size_t)(k0+j)*128 + col]);
}

// ---- pack LSTM weights: group g owns cols {gate*128 + g*16 + 0..15}, gate=ct
// f = g*2048 + ks*256 + ct*64 + l ; B[k][abscol], k<128->W_ih[c][k] else W_hh[c][k-128]
__global__ __launch_bounds__(256) void k_wtpack2(const float* __restrict__ W_ih,
                                                 const float* __restrict__ W_hh,
                                                 unsigned short* __restrict__ WP2){
    int f = blockIdx.x*256 + threadIdx.x;      // 16384 thread-frags
    int l = f&63, ct = (f>>6)&3, ks = (f>>8)&7, g = f>>11;
    int k0 = ks*32 + (l>>4)*8;
    int col = ct*128 + g*16 + (l&15);
    #pragma unroll
    for(int j=0;j<8;j++){
        int k = k0+j;
        float w = (k<128) ? W_ih[(size_t)col*128+k] : W_hh[(size_t)col*128+(k-128)];
        WP2[(size_t)f*8+j] = f2bf(w);
    }
}

// ---- xs = x @ W via MFMA, B-in-registers, no LDS/barriers.
// wave owns all 128 cols (32 B-frags); grid-strides 16-row tiles.
__global__ __launch_bounds__(256,2) void k_gemm_xs2(const float* __restrict__ x,
                                                    const unsigned short* __restrict__ WPX,
                                                    float* __restrict__ xs,
                                                    int n, int ntiles, int nwaves){
    const int w = threadIdx.x>>6, l = threadIdx.x&63;
    const int wid = blockIdx.x*4 + w;
    bf16x8 B[32];
    #pragma unroll
    for(int f=0;f<32;f++) B[f] = *(const bf16x8*)(WPX + (size_t)(f*64 + l)*8);
    for(int rt = wid; rt < ntiles; rt += nwaves){
        int arow = rt*16 + (l&15); if(arow>=n) arow = n-1;
        const float* xr = x + (size_t)arow*128 + (l>>4)*8;
        bf16x8 A[4];
        #pragma unroll
        for(int ks=0;ks<4;ks++){
            float4 u = *(const float4*)(xr + ks*32);
            float4 v = *(const float4*)(xr + ks*32 + 4);
            A[ks] = pack8(u,v);
        }
        f32x4 acc[8];
        #pragma unroll
        for(int ct=0;ct<8;ct++) acc[ct] = (f32x4){0.f,0.f,0.f,0.f};
        #pragma unroll
        for(int ks=0;ks<4;ks++){
            #pragma unroll
            for(int ct=0;ct<8;ct++)
                acc[ct] = __builtin_amdgcn_mfma_f32_16x16x32_bf16(A[ks], B[ks*8+ct], acc[ct], 0,0,0);
        }
        #pragma unroll
        for(int ct=0;ct<8;ct++){
            int col = ct*16 + (l&15);
            #pragma unroll
            for(int reg=0;reg<4;reg++){
                int row = rt*16 + (l>>4)*4 + reg;
                if(row<n) xs[(size_t)row*128 + col] = acc[ct][reg];
            }
        }
    }
}

// ---- K3: a_src[row] = xs[row,:]·att_src ; a_dst likewise. One wave per row.
__global__ __launch_bounds__(256) void k_attdot(const float* __restrict__ xs,
                                                const float* __restrict__ as,
                                                const float* __restrict__ ad,
                                                float* __restrict__ a_src,
                                                float* __restrict__ a_dst, int n){
    const int wv = threadIdx.x>>6, l = threadIdx.x&63;
    const int row = blockIdx.x*4 + wv;
    if(row>=n) return;
    float x0 = xs[(size_t)row*128+l], x1 = xs[(size_t)row*128+64+l];
    float ps = x0*as[l] + x1*as[64+l];
    float pd = x0*ad[l] + x1*ad[64+l];
    for(int off=32;off;off>>=1){ ps += __shfl_xor(ps,off); pd += __shfl_xor(pd,off); }
    if(l==0){ a_src[row]=ps; a_dst[row]=pd; }
}

// ---- fill xhg[:,128:256] = bf16(h0)
__global__ __launch_bounds__(256) void k_xh(const float* __restrict__ h0,
                                            unsigned short* __restrict__ xhg, int n){
    int idx = blockIdx.x*256 + threadIdx.x;    // n*16 chunks of 8
    if(idx >= n*16) return;
    int row = idx>>4, kk = (idx&15)*8;
    float4 u = *(const float4*)(h0 + (size_t)row*128 + kk);
    float4 v = *(const float4*)(h0 + (size_t)row*128 + kk + 4);
    bf16x8 p = pack8(u,v);
    *(bf16x8*)(xhg + (size_t)row*256 + 128 + kk) = p;
}

// ---- CSR build: histogram of dst (self-loops appended: dst = e-E)
__global__ __launch_bounds__(256) void k_hist(const int* __restrict__ ei,
                                              const int* __restrict__ flag,
                                              int* __restrict__ deg, int E, int EN){
    int e = blockIdx.x*256 + threadIdx.x;
    if(e>=EN) return;
    int dst = (e>=E) ? (e-E) : (*flag ? ei[2*(E+e)] : ei[E+e]);
    atomicAdd(&deg[dst], 1);
}

// ---- scan level 1: per-512-chunk sums
__global__ __launch_bounds__(256) void k_scan1(const int* __restrict__ deg,
                                               int* __restrict__ bsum, int n){
    __shared__ int ws[4];
    int b = blockIdx.x, t = threadIdx.x;
    int i = b*512 + t*2;
    int s = 0;
    if(i<n)   s += deg[i];
    if(i+1<n) s += deg[i+1];
    for(int off=32;off;off>>=1) s += __shfl_xor(s,off);
    if((t&63)==0) ws[t>>6]=s;
    __syncthreads();
    if(t==0) bsum[b]=ws[0]+ws[1]+ws[2]+ws[3];
}

// ---- scan level 2: exclusive scan of up to 128 block sums (one wave)
__global__ void k_scan2(int* __restrict__ bsum, int* __restrict__ rowptr,
                        int nb, int n, int EN){
    int t = threadIdx.x;  // 64
    int v0 = (t<nb)    ? bsum[t]    : 0;
    int v1 = (64+t<nb) ? bsum[64+t] : 0;
    int x = v0;
    for(int d=1; d<64; d<<=1){ int y=__shfl_up(x,d); if(t>=d) x+=y; }
    int tot0 = __shfl(x,63);
    int x1 = v1;
    for(int d=1; d<64; d<<=1){ int y=__shfl_up(x1,d); if(t>=d) x1+=y; }
    if(t<nb)    bsum[t]    = x - v0;
    if(64+t<nb) bsum[64+t] = tot0 + x1 - v1;
    if(t==0) rowptr[n]=EN;
}

// ---- scan level 3: in-chunk exclusive scan + block offset -> rowptr, cursor
__global__ __launch_bounds__(256) void k_scan3(const int* __restrict__ deg,
                                               const int* __restrict__ bsum,
                                               int* __restrict__ rowptr,
                                               int* __restrict__ cursor, int n){
    __shared__ int wsum[4];
    int b = blockIdx.x, t = threadIdx.x;
    int i = b*512 + t*2;
    int d0 = (i<n)?deg[i]:0, d1 = (i+1<n)?deg[i+1]:0;
    int s = d0+d1;
    int x = s;
    int lane = t&63, wv = t>>6;
    for(int dd=1; dd<64; dd<<=1){ int y=__shfl_up(x,dd); if(lane>=dd) x+=y; }
    if(lane==63) wsum[wv]=x;
    __syncthreads();
    int woff=0;
    for(int w=0;w<wv;w++) woff += wsum[w];
    int ex = bsum[b] + woff + x - s;     // exclusive prefix for element i
    if(i<n)   { rowptr[i]  =ex;    cursor[i]  =ex;    }
    if(i+1<n) { rowptr[i+1]=ex+d0; cursor[i+1]=ex+d0; }
}

// ---- fill CSR: csr_src[pos] = src for each edge grouped by dst
__global__ __launch_bounds__(256) void k_fill(const int* __restrict__ ei,
                                              const int* __restrict__ flag,
                                              int* __restrict__ cursor,
                                              int* __restrict__ csr_src, int E, int EN){
    int e = blockIdx.x*256 + threadIdx.x;
    if(e>=EN) return;
    int src,dst;
    if(e>=E){ src=dst=e-E; }
    else if(*flag){ src = ei[2*e]; dst = ei[2*(E+e)]; }
    else         { src = ei[e];   dst = ei[E+e]; }
    int pos = atomicAdd(&cursor[dst], 1);
    csr_src[pos] = src;
}

// ---- aggregate + fused GAT epilogue: xhg[dst, 0:128] = bf16(tanh(agg + bias_gat))
__global__ __launch_bounds__(256) void k_agg(const int* __restrict__ rowptr,
                                             const int* __restrict__ csr_src,
                                             const float* __restrict__ a_src,
                                             const float* __restrict__ a_dst,
                                             const float* __restrict__ xs,
                                             const float* __restrict__ bg,
                                             unsigned short* __restrict__ xhg, int n){
    const int wv = threadIdx.x>>6, l = threadIdx.x&63;
    const int dst = blockIdx.x*4 + wv;
    if(dst>=n) return;
    const int beg = rowptr[dst], end = rowptr[dst+1];
    const float ad = a_dst[dst];
    float ax=0.f, ay=0.f, psum=0.f;
    for(int j=beg;j<end;j++){
        int s = csr_src[j];
        float sv = a_src[s] + ad;
        sv = sv>=0.f ? sv : NEG*sv;
        float p = __expf(sv);
        psum += p;
        const float2 v = *(const float2*)&xs[(size_t)s*128 + 2*l];
        ax += p*v.x; ay += p*v.y;
    }
    const float inv = 1.0f/(psum + 1e-16f);
    float t0 = ftanh(ax*inv + bg[2*l]);
    float t1 = ftanh(ay*inv + bg[2*l+1]);
    unsigned int pk = (unsigned)f2bf(t0) | ((unsigned)f2bf(t1)<<16);
    ((unsigned int*)(xhg + (size_t)dst*256))[l] = pk;
}

// ---- LSTM via MFMA, B-in-registers, no LDS/barriers.
// wave -> col-group g (64 cols: 16 per gate), grid-strides 16-row tiles.
__global__ __launch_bounds__(256,2) void k_lstm3(const unsigned short* __restrict__ xhg,
                                                 const unsigned short* __restrict__ WP2,
                                                 const float* __restrict__ c0,
                                                 float* __restrict__ out,
                                                 int n, int ntiles){
    const int w = threadIdx.x>>6, l = threadIdx.x&63;
    const int wid = blockIdx.x*4 + w;          // 2048 waves
    const int g = wid & 7, wgi = wid >> 3;     // 8 col-groups x 256 waves
    const unsigned short* wp = WP2 + (size_t)g*16384;
    bf16x8 B[32];
    #pragma unroll
    for(int f=0;f<32;f++) B[f] = *(const bf16x8*)(wp + (size_t)(f*64 + l)*8);
    const size_t nn = (size_t)n*128;
    const int col = g*16 + (l&15);
    for(int rt = wgi; rt < ntiles; rt += 256){
        int arow = rt*16 + (l&15); if(arow>=n) arow = n-1;
        const unsigned short* ar = xhg + (size_t)arow*256 + (l>>4)*8;
        bf16x8 A[8];
        #pragma unroll
        for(int ks=0;ks<8;ks++) A[ks] = *(const bf16x8*)(ar + ks*32);
        f32x4 acc[4];
        #pragma unroll
        for(int ct=0;ct<4;ct++) acc[ct] = (f32x4){0.f,0.f,0.f,0.f};
        #pragma unroll
        for(int ks=0;ks<8;ks++){
            #pragma unroll
            for(int ct=0;ct<4;ct++)
                acc[ct] = __builtin_amdgcn_mfma_f32_16x16x32_bf16(A[ks], B[ks*4+ct], acc[ct], 0,0,0);
        }
        #pragma unroll
        for(int reg=0;reg<4;reg++){
            int row = rt*16 + (l>>4)*4 + reg;
            if(row>=n) continue;
            float gi = acc[0][reg], gf = acc[1][reg];
            float gg = acc[2][reg], go = acc[3][reg];
            float cc = c0[(size_t)row*128+col];
            float c1v = fsig(gf)*cc + fsig(gi)*ftanh(gg);
            float h1v = fsig(go)*ftanh(c1v);
            out[(size_t)row*128+col]        = h1v;
            out[nn + (size_t)row*128+col]   = h1v;
            out[2*nn + (size_t)row*128+col] = c1v;
        }
    }
}

extern "C" void kernel_launch(void* const* d_in, const int* in_sizes, int n_in,
                              void* d_out, int out_size, void* d_ws, size_t ws_size,
                              hipStream_t stream) {
    const float* x      = (const float*)d_in[0];
    const int*   ei     = (const int*)  d_in[1];
    const float* h      = (const float*)d_in[2];
    const float* c      = (const float*)d_in[3];
    const float* W      = (const float*)d_in[4];
    const float* atts   = (const float*)d_in[5];
    const float* attd   = (const float*)d_in[6];
    const float* bias   = (const float*)d_in[7];
    const float* W_ih   = (const float*)d_in[8];
    const float* W_hh   = (const float*)d_in[9];
    float* out = (float*)d_out;

    const int n  = in_sizes[0]/128;
    const int E  = in_sizes[1]/2;
    const int EN = E + n;
    const int NB = (n + 511)/512;
    const int ntiles = (n + 15)/16;
    const int n2 = ntiles*16;

    float* ws    = (float*)d_ws;
    float* xs    = ws;                                   // n*128 f32
    unsigned short* xhg = (unsigned short*)(xs + (size_t)n*128);   // n2*256 bf16
    unsigned short* WP2 = xhg + (size_t)n2*256;          // 131072 bf16 (256KB)
    unsigned short* WPX = WP2 + 131072;                  // 16384 bf16 (32KB)
    float* a_src = (float*)(WPX + 16384);                // n
    float* a_dst = a_src + n;                            // n
    int*   deg    = (int*)(a_dst + n);                   // n
    int*   rowptr = deg + n;                             // n+1
    int*   cursor = rowptr + n + 1;                      // n
    int*   bsum   = cursor + n;                          // 128
    int*   csr_src= bsum + 128;                          // EN
    int*   flag   = csr_src + EN;                        // 1

    hipMemsetAsync(deg, 0, (size_t)n*sizeof(int), stream);
    k_probe<<<1,64,0,stream>>>(ei, flag);
    k_wpackx<<<8,256,0,stream>>>(W, WPX);
    k_wtpack2<<<64,256,0,stream>>>(W_ih, W_hh, WP2);
    k_gemm_xs2<<<256,256,0,stream>>>(x, WPX, xs, n, ntiles, 1024);
    k_attdot<<<(n+3)/4,256,0,stream>>>(xs,atts,attd,a_src,a_dst,n);
    k_xh<<<(n*16+255)/256,256,0,stream>>>(h, xhg, n);
    k_hist<<<(EN+255)/256,256,0,stream>>>(ei,flag,deg,E,EN);
    k_scan1<<<NB,256,0,stream>>>(deg,bsum,n);
    k_scan2<<<1,64,0,stream>>>(bsum,rowptr,NB,n,EN);
    k_scan3<<<NB,256,0,stream>>>(deg,bsum,rowptr,cursor,n);
    k_fill<<<(EN+255)/256,256,0,stream>>>(ei,flag,cursor,csr_src,E,EN);
    k_agg<<<(n+3)/4,256,0,stream>>>(rowptr,csr_src,a_src,a_dst,xs,bias,xhg,n);
    k_lstm3<<<512,256,0,stream>>>(xhg, WP2, c, out, n, ntiles);
}

// Round 5
// 226.382 us; speedup vs baseline: 3.9958x; 1.0471x over previous
//
#include <hip/hip_runtime.h>
#include <hip/hip_bf16.h>
#include <math.h>

#define NEG 0.2f

typedef float f32x4 __attribute__((ext_vector_type(4)));
typedef short bf16x8 __attribute__((ext_vector_type(8)));

__device__ __forceinline__ float fsig(float x){ return 1.0f/(1.0f+__expf(-x)); }
__device__ __forceinline__ float ftanh(float x){ float e = __expf(2.0f*x); return 1.0f - 2.0f/(e+1.0f); }
__device__ __forceinline__ unsigned short f2bf(float v){
    __hip_bfloat16 b = __float2bfloat16(v);
    return *(unsigned short*)&b;
}
__device__ __forceinline__ bf16x8 pack8(float4 u, float4 v){
    bf16x8 r;
    r[0]=(short)f2bf(u.x); r[1]=(short)f2bf(u.y); r[2]=(short)f2bf(u.z); r[3]=(short)f2bf(u.w);
    r[4]=(short)f2bf(v.x); r[5]=(short)f2bf(v.y); r[6]=(short)f2bf(v.z); r[7]=(short)f2bf(v.w);
    return r;
}

// ---- K0: probe whether edge_index is stored as int64 (odd int32 words all 0) or int32
__global__ void k_probe(const int* __restrict__ ei, int* __restrict__ flag){
    if(threadIdx.x==0){
        int nz=0;
        for(int i=0;i<64;i++) nz |= ei[2*i+1];
        *flag = (nz==0) ? 1 : 0;  // 1 => int64 storage
    }
}

// ---- pack W (xs GEMM) into MFMA B-frag order
__global__ __launch_bounds__(256) void k_wpackx(const float* __restrict__ W,
                                                unsigned short* __restrict__ WPX){
    int f = blockIdx.x*256 + threadIdx.x;      // 2048 thread-frags
    int l = f&63, ct = (f>>6)&7, ks = f>>9;
    int k0 = ks*32 + (l>>4)*8;
    int col = ct*16 + (l&15);
    #pragma unroll
    for(int j=0;j<8;j++) WPX[(size_t)f*8+j] = f2bf(W[(size_t)(k0+j)*128 + col]);
}

// ---- pack LSTM weights: group g owns cols {gate*128 + g*16 + 0..15}
__global__ __launch_bounds__(256) void k_wtpack2(const float* __restrict__ W_ih,
                                                 const float* __restrict__ W_hh,
                                                 unsigned short* __restrict__ WP2){
    int f = blockIdx.x*256 + threadIdx.x;      // 16384 thread-frags
    int l = f&63, ct = (f>>6)&3, ks = (f>>8)&7, g = f>>11;
    int k0 = ks*32 + (l>>4)*8;
    int col = ct*128 + g*16 + (l&15);
    #pragma unroll
    for(int j=0;j<8;j++){
        int k = k0+j;
        float w = (k<128) ? W_ih[(size_t)col*128+k] : W_hh[(size_t)col*128+(k-128)];
        WP2[(size_t)f*8+j] = f2bf(w);
    }
}

// ---- xs GEMM via MFMA, B-in-registers; epilogue: bf16 xsb + fused att dots.
__global__ __launch_bounds__(256,2) void k_gemm_xs3(const float* __restrict__ x,
                                                    const unsigned short* __restrict__ WPX,
                                                    const float* __restrict__ att_s,
                                                    const float* __restrict__ att_d,
                                                    unsigned short* __restrict__ xsb,
                                                    float* __restrict__ a_src,
                                                    float* __restrict__ a_dst,
                                                    int n, int ntiles, int nwaves){
    const int w = threadIdx.x>>6, l = threadIdx.x&63;
    const int wid = blockIdx.x*4 + w;
    bf16x8 B[32];
    #pragma unroll
    for(int f=0;f<32;f++) B[f] = *(const bf16x8*)(WPX + (size_t)(f*64 + l)*8);
    float asv[8], adv[8];
    #pragma unroll
    for(int ct=0;ct<8;ct++){
        asv[ct] = att_s[ct*16 + (l&15)];
        adv[ct] = att_d[ct*16 + (l&15)];
    }
    for(int rt = wid; rt < ntiles; rt += nwaves){
        int arow = rt*16 + (l&15); if(arow>=n) arow = n-1;
        const float* xr = x + (size_t)arow*128 + (l>>4)*8;
        bf16x8 A[4];
        #pragma unroll
        for(int ks=0;ks<4;ks++){
            float4 u = *(const float4*)(xr + ks*32);
            float4 v = *(const float4*)(xr + ks*32 + 4);
            A[ks] = pack8(u,v);
        }
        f32x4 acc[8];
        #pragma unroll
        for(int ct=0;ct<8;ct++) acc[ct] = (f32x4){0.f,0.f,0.f,0.f};
        #pragma unroll
        for(int ks=0;ks<4;ks++){
            #pragma unroll
            for(int ct=0;ct<8;ct++)
                acc[ct] = __builtin_amdgcn_mfma_f32_16x16x32_bf16(A[ks], B[ks*8+ct], acc[ct], 0,0,0);
        }
        #pragma unroll
        for(int reg=0;reg<4;reg++){
            int row = rt*16 + (l>>4)*4 + reg;
            float ps=0.f, pd=0.f;
            #pragma unroll
            for(int ct=0;ct<8;ct++){ ps += acc[ct][reg]*asv[ct]; pd += acc[ct][reg]*adv[ct]; }
            ps += __shfl_xor(ps,1); pd += __shfl_xor(pd,1);
            ps += __shfl_xor(ps,2); pd += __shfl_xor(pd,2);
            ps += __shfl_xor(ps,4); pd += __shfl_xor(pd,4);
            ps += __shfl_xor(ps,8); pd += __shfl_xor(pd,8);
            if((l&15)==0 && row<n){ a_src[row]=ps; a_dst[row]=pd; }
            if(row<n){
                #pragma unroll
                for(int ct=0;ct<8;ct++)
                    xsb[(size_t)row*128 + ct*16 + (l&15)] = f2bf(acc[ct][reg]);
            }
        }
    }
}

// ---- CSR build: histogram of dst (self-loops appended: dst = e-E)
__global__ __launch_bounds__(256) void k_hist(const int* __restrict__ ei,
                                              const int* __restrict__ flag,
                                              int* __restrict__ deg, int E, int EN){
    int e = blockIdx.x*256 + threadIdx.x;
    if(e>=EN) return;
    int dst = (e>=E) ? (e-E) : (*flag ? ei[2*(E+e)] : ei[E+e]);
    atomicAdd(&deg[dst], 1);
}

// ---- scan level 1: per-512-chunk sums
__global__ __launch_bounds__(256) void k_scan1(const int* __restrict__ deg,
                                               int* __restrict__ bsum, int n){
    __shared__ int ws[4];
    int b = blockIdx.x, t = threadIdx.x;
    int i = b*512 + t*2;
    int s = 0;
    if(i<n)   s += deg[i];
    if(i+1<n) s += deg[i+1];
    for(int off=32;off;off>>=1) s += __shfl_xor(s,off);
    if((t&63)==0) ws[t>>6]=s;
    __syncthreads();
    if(t==0) bsum[b]=ws[0]+ws[1]+ws[2]+ws[3];
}

// ---- scan level 2: exclusive scan of up to 128 block sums (one wave)
__global__ void k_scan2(int* __restrict__ bsum, int* __restrict__ rowptr,
                        int nb, int n, int EN){
    int t = threadIdx.x;  // 64
    int v0 = (t<nb)    ? bsum[t]    : 0;
    int v1 = (64+t<nb) ? bsum[64+t] : 0;
    int x = v0;
    for(int d=1; d<64; d<<=1){ int y=__shfl_up(x,d); if(t>=d) x+=y; }
    int tot0 = __shfl(x,63);
    int x1 = v1;
    for(int d=1; d<64; d<<=1){ int y=__shfl_up(x1,d); if(t>=d) x1+=y; }
    if(t<nb)    bsum[t]    = x - v0;
    if(64+t<nb) bsum[64+t] = tot0 + x1 - v1;
    if(t==0) rowptr[n]=EN;
}

// ---- scan level 3: in-chunk exclusive scan + block offset -> rowptr, cursor
__global__ __launch_bounds__(256) void k_scan3(const int* __restrict__ deg,
                                               const int* __restrict__ bsum,
                                               int* __restrict__ rowptr,
                                               int* __restrict__ cursor, int n){
    __shared__ int wsum[4];
    int b = blockIdx.x, t = threadIdx.x;
    int i = b*512 + t*2;
    int d0 = (i<n)?deg[i]:0, d1 = (i+1<n)?deg[i+1]:0;
    int s = d0+d1;
    int x = s;
    int lane = t&63, wv = t>>6;
    for(int dd=1; dd<64; dd<<=1){ int y=__shfl_up(x,dd); if(lane>=dd) x+=y; }
    if(lane==63) wsum[wv]=x;
    __syncthreads();
    int woff=0;
    for(int w=0;w<wv;w++) woff += wsum[w];
    int ex = bsum[b] + woff + x - s;
    if(i<n)   { rowptr[i]  =ex;    cursor[i]  =ex;    }
    if(i+1<n) { rowptr[i+1]=ex+d0; cursor[i+1]=ex+d0; }
}

// ---- fill CSR: csr_src[pos] = src for each edge grouped by dst
__global__ __launch_bounds__(256) void k_fill(const int* __restrict__ ei,
                                              const int* __restrict__ flag,
                                              int* __restrict__ cursor,
                                              int* __restrict__ csr_src, int E, int EN){
    int e = blockIdx.x*256 + threadIdx.x;
    if(e>=EN) return;
    int src,dst;
    if(e>=E){ src=dst=e-E; }
    else if(*flag){ src = ei[2*e]; dst = ei[2*(E+e)]; }
    else         { src = ei[e];   dst = ei[E+e]; }
    int pos = atomicAdd(&cursor[dst], 1);
    csr_src[pos] = src;
}

// ---- aggregate (bf16 gather) + fused GAT epilogue -> xg = bf16(tanh(agg+bias))
__global__ __launch_bounds__(256) void k_agg2(const int* __restrict__ rowptr,
                                              const int* __restrict__ csr_src,
                                              const float* __restrict__ a_src,
                                              const float* __restrict__ a_dst,
                                              const unsigned int* __restrict__ xsb32,
                                              const float* __restrict__ bg,
                                              unsigned short* __restrict__ xg, int n){
    const int wv = threadIdx.x>>6, l = threadIdx.x&63;
    const int dst = blockIdx.x*4 + wv;
    if(dst>=n) return;
    const int beg = rowptr[dst], end = rowptr[dst+1];
    const float ad = a_dst[dst];
    float ax=0.f, ay=0.f, psum=0.f;
    for(int j=beg;j<end;j++){
        int s = csr_src[j];
        float sv = a_src[s] + ad;
        sv = sv>=0.f ? sv : NEG*sv;
        float p = __expf(sv);
        psum += p;
        unsigned pk = xsb32[(size_t)s*64 + l];
        ax += p*__uint_as_float(pk<<16);
        ay += p*__uint_as_float(pk & 0xffff0000u);
    }
    const float inv = 1.0f/(psum + 1e-16f);
    float t0 = ftanh(ax*inv + bg[2*l]);
    float t1 = ftanh(ay*inv + bg[2*l+1]);
    unsigned int pk = (unsigned)f2bf(t0) | ((unsigned)f2bf(t1)<<16);
    ((unsigned int*)(xg + (size_t)dst*128))[l] = pk;
}

// ---- LSTM via MFMA, B-in-registers; A = [xg bf16 | pack(h0 f32)]
__global__ __launch_bounds__(256,2) void k_lstm4(const unsigned short* __restrict__ xg,
                                                 const float* __restrict__ h0,
                                                 const unsigned short* __restrict__ WP2,
                                                 const float* __restrict__ c0,
                                                 float* __restrict__ out,
                                                 int n, int ntiles){
    const int w = threadIdx.x>>6, l = threadIdx.x&63;
    const int wid = blockIdx.x*4 + w;          // 2048 waves
    const int g = wid & 7, wgi = wid >> 3;     // 8 col-groups x 256 waves
    const unsigned short* wp = WP2 + (size_t)g*16384;
    bf16x8 B[32];
    #pragma unroll
    for(int f=0;f<32;f++) B[f] = *(const bf16x8*)(wp + (size_t)(f*64 + l)*8);
    const size_t nn = (size_t)n*128;
    const int col = g*16 + (l&15);
    for(int rt = wgi; rt < ntiles; rt += 256){
        int arow = rt*16 + (l&15); if(arow>=n) arow = n-1;
        const unsigned short* ar = xg + (size_t)arow*128 + (l>>4)*8;
        const float* hr = h0 + (size_t)arow*128 + (l>>4)*8;
        bf16x8 A[8];
        #pragma unroll
        for(int ks=0;ks<4;ks++) A[ks] = *(const bf16x8*)(ar + ks*32);
        #pragma unroll
        for(int ks=0;ks<4;ks++){
            float4 u = *(const float4*)(hr + ks*32);
            float4 v = *(const float4*)(hr + ks*32 + 4);
            A[4+ks] = pack8(u,v);
        }
        f32x4 acc[4];
        #pragma unroll
        for(int ct=0;ct<4;ct++) acc[ct] = (f32x4){0.f,0.f,0.f,0.f};
        #pragma unroll
        for(int ks=0;ks<8;ks++){
            #pragma unroll
            for(int ct=0;ct<4;ct++)
                acc[ct] = __builtin_amdgcn_mfma_f32_16x16x32_bf16(A[ks], B[ks*4+ct], acc[ct], 0,0,0);
        }
        #pragma unroll
        for(int reg=0;reg<4;reg++){
            int row = rt*16 + (l>>4)*4 + reg;
            if(row>=n) continue;
            float gi = acc[0][reg], gf = acc[1][reg];
            float gg = acc[2][reg], go = acc[3][reg];
            float cc = c0[(size_t)row*128+col];
            float c1v = fsig(gf)*cc + fsig(gi)*ftanh(gg);
            float h1v = fsig(go)*ftanh(c1v);
            out[(size_t)row*128+col]        = h1v;
            out[nn + (size_t)row*128+col]   = h1v;
            out[2*nn + (size_t)row*128+col] = c1v;
        }
    }
}

extern "C" void kernel_launch(void* const* d_in, const int* in_sizes, int n_in,
                              void* d_out, int out_size, void* d_ws, size_t ws_size,
                              hipStream_t stream) {
    const float* x      = (const float*)d_in[0];
    const int*   ei     = (const int*)  d_in[1];
    const float* h      = (const float*)d_in[2];
    const float* c      = (const float*)d_in[3];
    const float* W      = (const float*)d_in[4];
    const float* atts   = (const float*)d_in[5];
    const float* attd   = (const float*)d_in[6];
    const float* bias   = (const float*)d_in[7];
    const float* W_ih   = (const float*)d_in[8];
    const float* W_hh   = (const float*)d_in[9];
    float* out = (float*)d_out;

    const int n  = in_sizes[0]/128;
    const int E  = in_sizes[1]/2;
    const int EN = E + n;
    const int NB = (n + 511)/512;
    const int ntiles = (n + 15)/16;
    const int n2 = ntiles*16;

    unsigned short* xsb = (unsigned short*)d_ws;          // n*128 bf16
    unsigned short* xg  = xsb + (size_t)n*128;            // n2*128 bf16
    unsigned short* WP2 = xg + (size_t)n2*128;            // 131072 bf16
    unsigned short* WPX = WP2 + 131072;                   // 16384 bf16
    float* a_src = (float*)(WPX + 16384);                 // n
    float* a_dst = a_src + n;                             // n
    int*   deg    = (int*)(a_dst + n);                    // n
    int*   rowptr = deg + n;                              // n+1
    int*   cursor = rowptr + n + 1;                       // n
    int*   bsum   = cursor + n;                           // 128
    int*   csr_src= bsum + 128;                           // EN
    int*   flag   = csr_src + EN;                         // 1

    hipMemsetAsync(deg, 0, (size_t)n*sizeof(int), stream);
    k_probe<<<1,64,0,stream>>>(ei, flag);
    k_wpackx<<<8,256,0,stream>>>(W, WPX);
    k_wtpack2<<<64,256,0,stream>>>(W_ih, W_hh, WP2);
    k_gemm_xs3<<<256,256,0,stream>>>(x, WPX, atts, attd, xsb, a_src, a_dst, n, ntiles, 1024);
    k_hist<<<(EN+255)/256,256,0,stream>>>(ei,flag,deg,E,EN);
    k_scan1<<<NB,256,0,stream>>>(deg,bsum,n);
    k_scan2<<<1,64,0,stream>>>(bsum,rowptr,NB,n,EN);
    k_scan3<<<NB,256,0,stream>>>(deg,bsum,rowptr,cursor,n);
    k_fill<<<(EN+255)/256,256,0,stream>>>(ei,flag,cursor,csr_src,E,EN);
    k_agg2<<<(n+3)/4,256,0,stream>>>(rowptr,csr_src,a_src,a_dst,(const unsigned int*)xsb,bias,xg,n);
    k_lstm4<<<512,256,0,stream>>>(xg, h, WP2, c, out, n, ntiles);
}

// Round 6
// 178.909 us; speedup vs baseline: 5.0561x; 1.2654x over previous
//
#include <hip/hip_runtime.h>
#include <hip/hip_bf16.h>
#include <math.h>

#define NEG 0.2f

typedef float f32x4 __attribute__((ext_vector_type(4)));
typedef short bf16x8 __attribute__((ext_vector_type(8)));

__device__ __forceinline__ float fsig(float x){ return 1.0f/(1.0f+__expf(-x)); }
__device__ __forceinline__ float ftanh(float x){ float e = __expf(2.0f*x); return 1.0f - 2.0f/(e+1.0f); }
__device__ __forceinline__ unsigned short f2bf(float v){
    __hip_bfloat16 b = __float2bfloat16(v);
    return *(unsigned short*)&b;
}
__device__ __forceinline__ bf16x8 pack8(float4 u, float4 v){
    bf16x8 r;
    r[0]=(short)f2bf(u.x); r[1]=(short)f2bf(u.y); r[2]=(short)f2bf(u.z); r[3]=(short)f2bf(u.w);
    r[4]=(short)f2bf(v.x); r[5]=(short)f2bf(v.y); r[6]=(short)f2bf(v.z); r[7]=(short)f2bf(v.w);
    return r;
}

// ---- K0: probe whether edge_index is stored as int64 (odd int32 words all 0) or int32
__global__ void k_probe(const int* __restrict__ ei, int* __restrict__ flag){
    if(threadIdx.x==0){
        int nz=0;
        for(int i=0;i<64;i++) nz |= ei[2*i+1];
        *flag = (nz==0) ? 1 : 0;  // 1 => int64 storage
    }
}

// ---- pack W (xs GEMM) into MFMA B-frag order
__global__ __launch_bounds__(256) void k_wpackx(const float* __restrict__ W,
                                                unsigned short* __restrict__ WPX){
    int f = blockIdx.x*256 + threadIdx.x;      // 2048 thread-frags
    int l = f&63, ct = (f>>6)&7, ks = f>>9;
    int k0 = ks*32 + (l>>4)*8;
    int col = ct*16 + (l&15);
    #pragma unroll
    for(int j=0;j<8;j++) WPX[(size_t)f*8+j] = f2bf(W[(size_t)(k0+j)*128 + col]);
}

// ---- pack LSTM weights: group g owns cols {gate*128 + g*16 + 0..15}
__global__ __launch_bounds__(256) void k_wtpack2(const float* __restrict__ W_ih,
                                                 const float* __restrict__ W_hh,
                                                 unsigned short* __restrict__ WP2){
    int f = blockIdx.x*256 + threadIdx.x;      // 16384 thread-frags
    int l = f&63, ct = (f>>6)&3, ks = (f>>8)&7, g = f>>11;
    int k0 = ks*32 + (l>>4)*8;
    int col = ct*128 + g*16 + (l&15);
    #pragma unroll
    for(int j=0;j<8;j++){
        int k = k0+j;
        float w = (k<128) ? W_ih[(size_t)col*128+k] : W_hh[(size_t)col*128+(k-128)];
        WP2[(size_t)f*8+j] = f2bf(w);
    }
}

// ---- xs GEMM via MFMA, B-in-registers; epilogue: bf16 xsb + fused att dots.
__global__ __launch_bounds__(256,2) void k_gemm_xs3(const float* __restrict__ x,
                                                    const unsigned short* __restrict__ WPX,
                                                    const float* __restrict__ att_s,
                                                    const float* __restrict__ att_d,
                                                    unsigned short* __restrict__ xsb,
                                                    float* __restrict__ a_src,
                                                    float* __restrict__ a_dst,
                                                    int n, int ntiles, int nwaves){
    const int w = threadIdx.x>>6, l = threadIdx.x&63;
    const int wid = blockIdx.x*4 + w;
    bf16x8 B[32];
    #pragma unroll
    for(int f=0;f<32;f++) B[f] = *(const bf16x8*)(WPX + (size_t)(f*64 + l)*8);
    float asv[8], adv[8];
    #pragma unroll
    for(int ct=0;ct<8;ct++){
        asv[ct] = att_s[ct*16 + (l&15)];
        adv[ct] = att_d[ct*16 + (l&15)];
    }
    for(int rt = wid; rt < ntiles; rt += nwaves){
        int arow = rt*16 + (l&15); if(arow>=n) arow = n-1;
        const float* xr = x + (size_t)arow*128 + (l>>4)*8;
        bf16x8 A[4];
        #pragma unroll
        for(int ks=0;ks<4;ks++){
            float4 u = *(const float4*)(xr + ks*32);
            float4 v = *(const float4*)(xr + ks*32 + 4);
            A[ks] = pack8(u,v);
        }
        f32x4 acc[8];
        #pragma unroll
        for(int ct=0;ct<8;ct++) acc[ct] = (f32x4){0.f,0.f,0.f,0.f};
        #pragma unroll
        for(int ks=0;ks<4;ks++){
            #pragma unroll
            for(int ct=0;ct<8;ct++)
                acc[ct] = __builtin_amdgcn_mfma_f32_16x16x32_bf16(A[ks], B[ks*8+ct], acc[ct], 0,0,0);
        }
        #pragma unroll
        for(int reg=0;reg<4;reg++){
            int row = rt*16 + (l>>4)*4 + reg;
            float ps=0.f, pd=0.f;
            #pragma unroll
            for(int ct=0;ct<8;ct++){ ps += acc[ct][reg]*asv[ct]; pd += acc[ct][reg]*adv[ct]; }
            ps += __shfl_xor(ps,1); pd += __shfl_xor(pd,1);
            ps += __shfl_xor(ps,2); pd += __shfl_xor(pd,2);
            ps += __shfl_xor(ps,4); pd += __shfl_xor(pd,4);
            ps += __shfl_xor(ps,8); pd += __shfl_xor(pd,8);
            if((l&15)==0 && row<n){ a_src[row]=ps; a_dst[row]=pd; }
            if(row<n){
                #pragma unroll
                for(int ct=0;ct<8;ct++)
                    xsb[(size_t)row*128 + ct*16 + (l&15)] = f2bf(acc[ct][reg]);
            }
        }
    }
}

// ---- CSR build: histogram of dst (self-loops appended: dst = e-E)
__global__ __launch_bounds__(256) void k_hist(const int* __restrict__ ei,
                                              const int* __restrict__ flag,
                                              int* __restrict__ deg, int E, int EN){
    int e = blockIdx.x*256 + threadIdx.x;
    if(e>=EN) return;
    int dst = (e>=E) ? (e-E) : (*flag ? ei[2*(E+e)] : ei[E+e]);
    atomicAdd(&deg[dst], 1);
}

// ---- scan level 1: per-512-chunk sums
__global__ __launch_bounds__(256) void k_scan1(const int* __restrict__ deg,
                                               int* __restrict__ bsum, int n){
    __shared__ int ws[4];
    int b = blockIdx.x, t = threadIdx.x;
    int i = b*512 + t*2;
    int s = 0;
    if(i<n)   s += deg[i];
    if(i+1<n) s += deg[i+1];
    for(int off=32;off;off>>=1) s += __shfl_xor(s,off);
    if((t&63)==0) ws[t>>6]=s;
    __syncthreads();
    if(t==0) bsum[b]=ws[0]+ws[1]+ws[2]+ws[3];
}

// ---- scan level 2: exclusive scan of up to 128 block sums (one wave)
__global__ void k_scan2(int* __restrict__ bsum, int* __restrict__ rowptr,
                        int nb, int n, int EN){
    int t = threadIdx.x;  // 64
    int v0 = (t<nb)    ? bsum[t]    : 0;
    int v1 = (64+t<nb) ? bsum[64+t] : 0;
    int x = v0;
    for(int d=1; d<64; d<<=1){ int y=__shfl_up(x,d); if(t>=d) x+=y; }
    int tot0 = __shfl(x,63);
    int x1 = v1;
    for(int d=1; d<64; d<<=1){ int y=__shfl_up(x1,d); if(t>=d) x1+=y; }
    if(t<nb)    bsum[t]    = x - v0;
    if(64+t<nb) bsum[64+t] = tot0 + x1 - v1;
    if(t==0) rowptr[n]=EN;
}

// ---- scan level 3: in-chunk exclusive scan + block offset -> rowptr, cursor
__global__ __launch_bounds__(256) void k_scan3(const int* __restrict__ deg,
                                               const int* __restrict__ bsum,
                                               int* __restrict__ rowptr,
                                               int* __restrict__ cursor, int n){
    __shared__ int wsum[4];
    int b = blockIdx.x, t = threadIdx.x;
    int i = b*512 + t*2;
    int d0 = (i<n)?deg[i]:0, d1 = (i+1<n)?deg[i+1]:0;
    int s = d0+d1;
    int x = s;
    int lane = t&63, wv = t>>6;
    for(int dd=1; dd<64; dd<<=1){ int y=__shfl_up(x,dd); if(lane>=dd) x+=y; }
    if(lane==63) wsum[wv]=x;
    __syncthreads();
    int woff=0;
    for(int w=0;w<wv;w++) woff += wsum[w];
    int ex = bsum[b] + woff + x - s;
    if(i<n)   { rowptr[i]  =ex;    cursor[i]  =ex;    }
    if(i+1<n) { rowptr[i+1]=ex+d0; cursor[i+1]=ex+d0; }
}

// ---- fill CSR: csr_src[pos] = src for each edge grouped by dst
__global__ __launch_bounds__(256) void k_fill(const int* __restrict__ ei,
                                              const int* __restrict__ flag,
                                              int* __restrict__ cursor,
                                              int* __restrict__ csr_src, int E, int EN){
    int e = blockIdx.x*256 + threadIdx.x;
    if(e>=EN) return;
    int src,dst;
    if(e>=E){ src=dst=e-E; }
    else if(*flag){ src = ei[2*e]; dst = ei[2*(E+e)]; }
    else         { src = ei[e];   dst = ei[E+e]; }
    int pos = atomicAdd(&cursor[dst], 1);
    csr_src[pos] = src;
}

// ---- aggregate (bf16 gather, unroll-4) + GAT epilogue + h0 pack
// xh[dst, 0:128] = bf16(tanh(agg+bias)); xh[dst, 128:256] = bf16(h0[dst])
__global__ __launch_bounds__(256) void k_agg3(const int* __restrict__ rowptr,
                                              const int* __restrict__ csr_src,
                                              const float* __restrict__ a_src,
                                              const float* __restrict__ a_dst,
                                              const unsigned int* __restrict__ xsb32,
                                              const float* __restrict__ bg,
                                              const float* __restrict__ h0,
                                              unsigned short* __restrict__ xh, int n){
    const int wv = threadIdx.x>>6, l = threadIdx.x&63;
    const int dst = blockIdx.x*4 + wv;
    if(dst>=n) return;
    const int beg = rowptr[dst], end = rowptr[dst+1];
    const float ad = a_dst[dst];
    float ax=0.f, ay=0.f, psum=0.f;
    int j = beg;
    for(; j+4<=end; j+=4){
        int s0=csr_src[j], s1=csr_src[j+1], s2=csr_src[j+2], s3=csr_src[j+3];
        float e0=a_src[s0]+ad, e1=a_src[s1]+ad, e2=a_src[s2]+ad, e3=a_src[s3]+ad;
        unsigned k0=xsb32[(size_t)s0*64+l], k1=xsb32[(size_t)s1*64+l];
        unsigned k2=xsb32[(size_t)s2*64+l], k3=xsb32[(size_t)s3*64+l];
        e0 = e0>=0.f?e0:NEG*e0; e1 = e1>=0.f?e1:NEG*e1;
        e2 = e2>=0.f?e2:NEG*e2; e3 = e3>=0.f?e3:NEG*e3;
        float p0=__expf(e0), p1=__expf(e1), p2=__expf(e2), p3=__expf(e3);
        psum += p0+p1+p2+p3;
        ax += p0*__uint_as_float(k0<<16) + p1*__uint_as_float(k1<<16)
            + p2*__uint_as_float(k2<<16) + p3*__uint_as_float(k3<<16);
        ay += p0*__uint_as_float(k0&0xffff0000u) + p1*__uint_as_float(k1&0xffff0000u)
            + p2*__uint_as_float(k2&0xffff0000u) + p3*__uint_as_float(k3&0xffff0000u);
    }
    for(; j<end; ++j){
        int s = csr_src[j];
        float sv = a_src[s]+ad;
        sv = sv>=0.f ? sv : NEG*sv;
        float p = __expf(sv);
        psum += p;
        unsigned pk = xsb32[(size_t)s*64 + l];
        ax += p*__uint_as_float(pk<<16);
        ay += p*__uint_as_float(pk & 0xffff0000u);
    }
    const float inv = 1.0f/(psum + 1e-16f);
    float t0 = ftanh(ax*inv + bg[2*l]);
    float t1 = ftanh(ay*inv + bg[2*l+1]);
    unsigned int pk = (unsigned)f2bf(t0) | ((unsigned)f2bf(t1)<<16);
    unsigned int* xr = (unsigned int*)(xh + (size_t)dst*256);
    xr[l] = pk;
    float2 hv = *(const float2*)(h0 + (size_t)dst*128 + 2*l);
    xr[64 + l] = (unsigned)f2bf(hv.x) | ((unsigned)f2bf(hv.y)<<16);
}

// ---- LSTM via MFMA, B-in-registers; A = xh[row, 0:256] contiguous bf16
__global__ __launch_bounds__(256,2) void k_lstm5(const unsigned short* __restrict__ xh,
                                                 const unsigned short* __restrict__ WP2,
                                                 const float* __restrict__ c0,
                                                 float* __restrict__ out,
                                                 int n, int ntiles, int wstride){
    const int w = threadIdx.x>>6, l = threadIdx.x&63;
    const int wid = blockIdx.x*4 + w;
    const int g = wid & 7, wgi = wid >> 3;     // 8 col-groups
    const unsigned short* wp = WP2 + (size_t)g*16384;
    bf16x8 B[32];
    #pragma unroll
    for(int f=0;f<32;f++) B[f] = *(const bf16x8*)(wp + (size_t)(f*64 + l)*8);
    const size_t nn = (size_t)n*128;
    const int col = g*16 + (l&15);
    for(int rt = wgi; rt < ntiles; rt += wstride){
        int arow = rt*16 + (l&15); if(arow>=n) arow = n-1;
        const unsigned short* ar = xh + (size_t)arow*256 + (l>>4)*8;
        bf16x8 A[8];
        #pragma unroll
        for(int ks=0;ks<8;ks++) A[ks] = *(const bf16x8*)(ar + ks*32);
        f32x4 acc[4];
        #pragma unroll
        for(int ct=0;ct<4;ct++) acc[ct] = (f32x4){0.f,0.f,0.f,0.f};
        #pragma unroll
        for(int ks=0;ks<8;ks++){
            #pragma unroll
            for(int ct=0;ct<4;ct++)
                acc[ct] = __builtin_amdgcn_mfma_f32_16x16x32_bf16(A[ks], B[ks*4+ct], acc[ct], 0,0,0);
        }
        #pragma unroll
        for(int reg=0;reg<4;reg++){
            int row = rt*16 + (l>>4)*4 + reg;
            if(row>=n) continue;
            float gi = acc[0][reg], gf = acc[1][reg];
            float gg = acc[2][reg], go = acc[3][reg];
            float cc = c0[(size_t)row*128+col];
            float c1v = fsig(gf)*cc + fsig(gi)*ftanh(gg);
            float h1v = fsig(go)*ftanh(c1v);
            out[(size_t)row*128+col]        = h1v;
            out[nn + (size_t)row*128+col]   = h1v;
            out[2*nn + (size_t)row*128+col] = c1v;
        }
    }
}

extern "C" void kernel_launch(void* const* d_in, const int* in_sizes, int n_in,
                              void* d_out, int out_size, void* d_ws, size_t ws_size,
                              hipStream_t stream) {
    const float* x      = (const float*)d_in[0];
    const int*   ei     = (const int*)  d_in[1];
    const float* h      = (const float*)d_in[2];
    const float* c      = (const float*)d_in[3];
    const float* W      = (const float*)d_in[4];
    const float* atts   = (const float*)d_in[5];
    const float* attd   = (const float*)d_in[6];
    const float* bias   = (const float*)d_in[7];
    const float* W_ih   = (const float*)d_in[8];
    const float* W_hh   = (const float*)d_in[9];
    float* out = (float*)d_out;

    const int n  = in_sizes[0]/128;
    const int E  = in_sizes[1]/2;
    const int EN = E + n;
    const int NB = (n + 511)/512;
    const int ntiles = (n + 15)/16;
    const int n2 = ntiles*16;

    unsigned short* xsb = (unsigned short*)d_ws;          // n*128 bf16
    unsigned short* xh  = xsb + (size_t)n*128;            // n2*256 bf16
    unsigned short* WP2 = xh + (size_t)n2*256;            // 131072 bf16
    unsigned short* WPX = WP2 + 131072;                   // 16384 bf16
    float* a_src = (float*)(WPX + 16384);                 // n
    float* a_dst = a_src + n;                             // n
    int*   deg    = (int*)(a_dst + n);                    // n
    int*   rowptr = deg + n;                              // n+1
    int*   cursor = rowptr + n + 1;                       // n
    int*   bsum   = cursor + n;                           // 128
    int*   csr_src= bsum + 128;                           // EN
    int*   flag   = csr_src + EN;                         // 1

    hipMemsetAsync(deg, 0, (size_t)n*sizeof(int), stream);
    k_probe<<<1,64,0,stream>>>(ei, flag);
    k_wpackx<<<8,256,0,stream>>>(W, WPX);
    k_wtpack2<<<64,256,0,stream>>>(W_ih, W_hh, WP2);
    k_gemm_xs3<<<1024,256,0,stream>>>(x, WPX, atts, attd, xsb, a_src, a_dst, n, ntiles, 4096);
    k_hist<<<(EN+255)/256,256,0,stream>>>(ei,flag,deg,E,EN);
    k_scan1<<<NB,256,0,stream>>>(deg,bsum,n);
    k_scan2<<<1,64,0,stream>>>(bsum,rowptr,NB,n,EN);
    k_scan3<<<NB,256,0,stream>>>(deg,bsum,rowptr,cursor,n);
    k_fill<<<(EN+255)/256,256,0,stream>>>(ei,flag,cursor,csr_src,E,EN);
    k_agg3<<<(n+3)/4,256,0,stream>>>(rowptr,csr_src,a_src,a_dst,(const unsigned int*)xsb,bias,h,xh,n);
    k_lstm5<<<1024,256,0,stream>>>(xh, WP2, c, out, n, ntiles, 512);
}